// Round 8
// baseline (225.573 us; speedup 1.0000x reference)
//
#include <hip/hip_runtime.h>

#define B_ 4
#define C_ 256
#define O_ 256
#define H_ 64
#define W_ 64
#define HW 4096
#define NOFF 18
#define CK 2304

typedef __bf16 bf16x8 __attribute__((ext_vector_type(8)));
typedef float f32x4 __attribute__((ext_vector_type(4)));

// ---------------------------------------------------------------------------
// wprep_def: one block per output row o; strided scatter covers all 288
// granules (36 ch x 8 g).  Wt4[ch*2048 + o*8 + (g^(o&7))].
// ---------------------------------------------------------------------------
__global__ __launch_bounds__(256) void wprep_def_kernel(
    const float* __restrict__ w_def, uint4* __restrict__ Wt4)
{
    __shared__ __bf16 wrow[CK];
    const int o = blockIdx.x;
    const int t = threadIdx.x;
#pragma unroll
    for (int q = 0; q < 9; ++q)
        wrow[t * 9 + q] = (__bf16)w_def[(size_t)o * CK + t * 9 + q];
    __syncthreads();
    for (int s = t; s < 288; s += 256) {
        const int ch = s >> 3, g = s & 7;
        const int kk = ch >> 2, cg = ch & 3;
        bf16x8 v;
#pragma unroll
        for (int j = 0; j < 8; ++j)
            v[j] = wrow[(cg * 64 + g * 8 + j) * 9 + kk];
        Wt4[(size_t)ch * 2048 + o * 8 + (g ^ (o & 7))] = __builtin_bit_cast(uint4, v);
    }
}

// ---------------------------------------------------------------------------
// wprep_woff: offset-conv weights, bf16, M padded 18->32, same swizzle.
// ---------------------------------------------------------------------------
__global__ __launch_bounds__(256) void wprep_woff_kernel(
    const float* __restrict__ w_off, uint4* __restrict__ Woff4)
{
    const int ch = blockIdx.x;                 // 0..35
    const int t = threadIdx.x;
    const int o = t >> 3, g = t & 7;           // o 0..31
    const int kk = ch >> 2, cg = ch & 3;
    bf16x8 v;
#pragma unroll
    for (int j = 0; j < 8; ++j) {
        const int c = cg * 64 + g * 8 + j;
        v[j] = (o < NOFF) ? (__bf16)w_off[(size_t)o * CK + c * 9 + kk] : (__bf16)0.f;
    }
    Woff4[(size_t)ch * 256 + o * 8 + (g ^ (o & 7))] = __builtin_bit_cast(uint4, v);
}

// ---------------------------------------------------------------------------
// Offset conv via MFMA, barrier-free main loop (unchanged from r7).
// ---------------------------------------------------------------------------
__global__ __launch_bounds__(256, 4) void offs_mfma_kernel(
    const float* __restrict__ x, const uint4* __restrict__ Woff4,
    const float* __restrict__ b_off, float* __restrict__ offs)
{
    __shared__ float red[2][32][16];

    const int i = blockIdx.x;
    const int l = ((i & 7) << 6) + (i >> 3);   // bijective, 64 blocks/XCD
    const int ph = l & 1;
    const int bh = l >> 1;
    const int b = bh >> 6, h = bh & 63;

    const int t = threadIdx.x;
    const int w = t >> 6, lane = t & 63;
    const int l15 = lane & 15, l4 = lane >> 4;
    const int pxg = w & 1, kh = w >> 1;
    const int px = ph * 32 + pxg * 16 + l15;
    const float* xb = x + (size_t)b * C_ * HW;

    f32x4 acc0 = {0.f, 0.f, 0.f, 0.f}, acc1 = {0.f, 0.f, 0.f, 0.f};

    for (int kk = 0; kk < 9; ++kk) {
        const int ky = kk / 3, kx = kk - 3 * ky;
        const int y = h + ky - 1;
        const int col = px + kx - 1;
        const bool valid = (y >= 0) && (y < H_) && (col >= 0) && (col < W_);
#pragma unroll
        for (int cgl = 0; cgl < 2; ++cgl) {
            const int cg = kh * 2 + cgl;
            const int ch = kk * 4 + cg;
#pragma unroll
            for (int st = 0; st < 2; ++st) {
                const int g = st * 4 + l4;
                const int r0 = l15, r1 = 16 + l15;
                const bf16x8 a0 = __builtin_bit_cast(bf16x8,
                    Woff4[(size_t)ch * 256 + r0 * 8 + (g ^ (r0 & 7))]);
                const bf16x8 a1 = __builtin_bit_cast(bf16x8,
                    Woff4[(size_t)ch * 256 + r1 * 8 + (g ^ (r1 & 7))]);
                bf16x8 bF;
                if (valid) {
                    const float* p = xb + (size_t)(cg * 64 + g * 8) * HW + y * W_ + col;
#pragma unroll
                    for (int j = 0; j < 8; ++j)
                        bF[j] = (__bf16)p[(size_t)j * HW];
                } else {
#pragma unroll
                    for (int j = 0; j < 8; ++j) bF[j] = (__bf16)0.f;
                }
                acc0 = __builtin_amdgcn_mfma_f32_16x16x32_bf16(a0, bF, acc0, 0, 0, 0);
                acc1 = __builtin_amdgcn_mfma_f32_16x16x32_bf16(a1, bF, acc1, 0, 0, 0);
            }
        }
    }

    if (kh == 1) {
#pragma unroll
        for (int r = 0; r < 4; ++r) {
            red[pxg][l4 * 4 + r][l15] = acc0[r];
            red[pxg][16 + l4 * 4 + r][l15] = acc1[r];
        }
    }
    __syncthreads();
    if (kh == 0) {
#pragma unroll
        for (int ii = 0; ii < 2; ++ii) {
            const f32x4 a = ii ? acc1 : acc0;
#pragma unroll
            for (int r = 0; r < 4; ++r) {
                const int oc = ii * 16 + l4 * 4 + r;
                if (oc < NOFF) {
                    const float v = a[r] + red[pxg][oc][l15] + b_off[oc];
                    offs[((size_t)(bh * 64) + px) * NOFF + oc] = v;
                }
            }
        }
    }
}

// ---------------------------------------------------------------------------
// Deform conv, px-split: grid 512 = (b,h) x px-half, 512 threads (8 waves),
// 2 blocks/CU (72KB LDS).  Block tile 256o x 32px; wave w owns o=[w*32,+32).
// Sampling done ONCE per (b,h) (threads<256: 32 px x 8 granules).
// Sl4 double-buffered -> ONE barrier per kk.  Offsets in registers.
// ---------------------------------------------------------------------------
__global__ __launch_bounds__(512, 4) void deform_mfma_kernel(
    const float* __restrict__ x, const float* __restrict__ offs,
    const uint4* __restrict__ Wt4, const float* __restrict__ b_def,
    float* __restrict__ out)
{
    __shared__ uint4 slab[4096];     // 64KB [8 rows][64 col][8 gran], gran=g^(col&7)
    __shared__ uint4 Sl4[2][256];    //  8KB double-buffered [32 px][8 gran]

    const int i = blockIdx.x;
    const int l = ((i & 7) << 6) + (i >> 3);   // px-halves of same (b,h) adjacent -> same XCD
    const int ph = l & 1;
    const int bh = l >> 1;
    const int b = bh >> 6, h = bh & 63;
    const int wb = h - 3;            // slab window rows [wb, wb+7]

    const int t = threadIdx.x;
    const int lane = t & 63;
    const int w = t >> 6;            // wave id = o-group (0..7)
    const int l15 = lane & 15, l4 = lane >> 4;

    const int sp = t & 63, sg8 = t >> 6;        // slab staging role (all threads)
    const int pl = t & 31, sgs = (t >> 5) & 7;  // sampling role (t<256)
    const bool sampler = (t < 256);

    const float* xb = x + (size_t)b * C_ * HW;

    // ---- offsets -> registers (sampling threads only; kk index static) ----
    float dyr[9], dxr[9];
    if (sampler) {
        const float* op = offs + ((size_t)(bh * 64) + ph * 32 + pl) * NOFF;
#pragma unroll
        for (int kk = 0; kk < 9; ++kk) {
            const float2 d = *reinterpret_cast<const float2*>(op + 2 * kk);
            dyr[kk] = d.x; dxr[kk] = d.y;
        }
    }

    auto stage_slab = [&](int cg) {
        const float* xc = xb + (size_t)(cg * 64 + sg8 * 8) * HW;
#pragma unroll
        for (int r = 0; r < 8; ++r) {
            const int yc = min(max(wb + r, 0), H_ - 1);
            bf16x8 v;
#pragma unroll
            for (int j = 0; j < 8; ++j)
                v[j] = (__bf16)xc[(size_t)j * HW + yc * W_ + sp];
            slab[(r * 64 + sp) * 8 + (sg8 ^ (sp & 7))] = __builtin_bit_cast(uint4, v);
        }
    };

    f32x4 acc[2][2];
#pragma unroll
    for (int ii = 0; ii < 2; ++ii)
#pragma unroll
        for (int j = 0; j < 2; ++j) acc[ii][j] = f32x4{0.f, 0.f, 0.f, 0.f};

    for (int cg = 0; cg < 4; ++cg) {
        if (cg != 0) __syncthreads();    // all slab reads of previous cg done
        stage_slab(cg);
        __syncthreads();                 // slab visible
        const float* xsg = xb + (size_t)(cg * 64 + sgs * 8) * HW;  // slow-path base
#pragma unroll
        for (int kk = 0; kk < 9; ++kk) {
            const int buf = kk & 1;
            const int ch = kk * 4 + cg;
            // ---- A-frags from pre-swizzled global Wt4 (all threads, issue early) ----
            uint4 aR[2][2];
#pragma unroll
            for (int st = 0; st < 2; ++st) {
                const int g = st * 4 + l4;
#pragma unroll
                for (int ii = 0; ii < 2; ++ii) {
                    const int row = w * 32 + ii * 16 + l15;
                    aR[st][ii] = Wt4[(size_t)ch * 2048 + row * 8 + (g ^ (row & 7))];
                }
            }
            // ---- bilinear sampling (threads < 256): 32 px x 8 granules ----
            if (sampler) {
                const int ky = kk / 3, kx = kk - 3 * ky;
                const float py = (float)(h + ky - 1) + dyr[kk];
                const float pxf = (float)(ph * 32 + pl + kx - 1) + dxr[kk];
                const float y0f = floorf(py), x0f = floorf(pxf);
                const float ly = py - y0f, lx = pxf - x0f;
                const int y0 = (int)y0f, x0 = (int)x0f;
                const int y1 = y0 + 1, x1 = x0 + 1;
                const bool vy0 = (y0 >= 0) && (y0 < H_), vy1 = (y1 >= 0) && (y1 < H_);
                const bool vx0 = (x0 >= 0) && (x0 < W_), vx1 = (x1 >= 0) && (x1 < W_);
                const float w00 = (vy0 && vx0) ? (1.f - ly) * (1.f - lx) : 0.f;
                const float w01 = (vy0 && vx1) ? (1.f - ly) * lx : 0.f;
                const float w10 = (vy1 && vx0) ? ly * (1.f - lx) : 0.f;
                const float w11 = (vy1 && vx1) ? ly * lx : 0.f;
                bf16x8 sv;
                if (y0 >= wb && y0 <= wb + 6) {
                    const int s0 = y0 - wb;
                    const int xc0 = min(max(x0, 0), W_ - 1);
                    const int xc1 = min(max(x1, 0), W_ - 1);
                    const int gx0 = sgs ^ (xc0 & 7), gx1 = sgs ^ (xc1 & 7);
                    const bf16x8 c00 = __builtin_bit_cast(bf16x8, slab[(s0 * 64 + xc0) * 8 + gx0]);
                    const bf16x8 c01 = __builtin_bit_cast(bf16x8, slab[(s0 * 64 + xc1) * 8 + gx1]);
                    const bf16x8 c10 = __builtin_bit_cast(bf16x8, slab[((s0 + 1) * 64 + xc0) * 8 + gx0]);
                    const bf16x8 c11 = __builtin_bit_cast(bf16x8, slab[((s0 + 1) * 64 + xc1) * 8 + gx1]);
#pragma unroll
                    for (int j = 0; j < 8; ++j) {
                        const float v = w00 * (float)c00[j] + w01 * (float)c01[j]
                                      + w10 * (float)c10[j] + w11 * (float)c11[j];
                        sv[j] = (__bf16)v;
                    }
                } else {
                    const int y0c = min(max(y0, 0), H_ - 1), y1c = min(max(y1, 0), H_ - 1);
                    const int xc0 = min(max(x0, 0), W_ - 1), xc1 = min(max(x1, 0), W_ - 1);
                    const int i00 = y0c * W_ + xc0, i01 = y0c * W_ + xc1;
                    const int i10 = y1c * W_ + xc0, i11 = y1c * W_ + xc1;
#pragma unroll
                    for (int j = 0; j < 8; ++j) {
                        const float* p = xsg + (size_t)j * HW;
                        const float v = w00 * p[i00] + w01 * p[i01]
                                      + w10 * p[i10] + w11 * p[i11];
                        sv[j] = (__bf16)v;
                    }
                }
                Sl4[buf][pl * 8 + (sgs ^ (pl & 7))] = __builtin_bit_cast(uint4, sv);
            }
            __syncthreads();             // Sl4[buf] visible (1 barrier per kk)
            // ---- 2 K-steps of MFMA ----
#pragma unroll
            for (int st = 0; st < 2; ++st) {
                const int g = st * 4 + l4;
                bf16x8 bF[2];
#pragma unroll
                for (int j = 0; j < 2; ++j) {
                    const int pr = j * 16 + l15;           // local px 0..31
                    bF[j] = __builtin_bit_cast(bf16x8, Sl4[buf][pr * 8 + (g ^ (pr & 7))]);
                }
#pragma unroll
                for (int ii = 0; ii < 2; ++ii)
#pragma unroll
                    for (int j = 0; j < 2; ++j)
                        acc[ii][j] = __builtin_amdgcn_mfma_f32_16x16x32_bf16(
                            __builtin_bit_cast(bf16x8, aR[st][ii]), bF[j],
                            acc[ii][j], 0, 0, 0);
            }
        }
    }

    // ---- epilogue: bias + store (C/D: row=(l>>4)*4+r, col=l&15) ----
#pragma unroll
    for (int ii = 0; ii < 2; ++ii) {
#pragma unroll
        for (int r = 0; r < 4; ++r) {
            const int o = w * 32 + ii * 16 + l4 * 4 + r;
            const float bias = b_def[o];
#pragma unroll
            for (int j = 0; j < 2; ++j) {
                const int p = ph * 32 + j * 16 + l15;
                out[(((size_t)(b * O_ + o)) * H_ + h) * W_ + p] = acc[ii][j][r] + bias;
            }
        }
    }
}

// ---------------------------------------------------------------------------
extern "C" void kernel_launch(void* const* d_in, const int* in_sizes, int n_in,
                              void* d_out, int out_size, void* d_ws, size_t ws_size,
                              hipStream_t stream) {
    const float* x     = (const float*)d_in[0];
    const float* w_off = (const float*)d_in[1];
    const float* b_off = (const float*)d_in[2];
    const float* w_def = (const float*)d_in[3];
    const float* b_def = (const float*)d_in[4];
    float* out = (float*)d_out;

    // ws: Wt4 (73728 uint4 = 1.125MB) | Woff4 (9216 uint4 = 144KB) | offs (1.18MB)
    uint4* Wt4   = (uint4*)d_ws;
    uint4* Woff4 = Wt4 + 73728;
    float* offs  = (float*)(Woff4 + 9216);

    wprep_def_kernel<<<256, 256, 0, stream>>>(w_def, Wt4);
    wprep_woff_kernel<<<36, 256, 0, stream>>>(w_off, Woff4);
    offs_mfma_kernel<<<512, 256, 0, stream>>>(x, Woff4, b_off, offs);
    deform_mfma_kernel<<<512, 512, 0, stream>>>(x, offs, Wt4, b_def, out);
}

// Round 10
// 137.177 us; speedup vs baseline: 1.6444x; 1.6444x over previous
//
#include <hip/hip_runtime.h>

#define B_ 4
#define C_ 256
#define O_ 256
#define H_ 64
#define W_ 64
#define HW 4096
#define NOFF 18
#define CK 2304

typedef __bf16 bf16x8 __attribute__((ext_vector_type(8)));
typedef float f32x4 __attribute__((ext_vector_type(4)));

// ---------------------------------------------------------------------------
// wprep_def: one block per output row o; strided scatter covers all 288
// granules (36 ch x 8 g).  Wt4[ch*2048 + o*8 + (g^(o&7))].
// ---------------------------------------------------------------------------
__global__ __launch_bounds__(256) void wprep_def_kernel(
    const float* __restrict__ w_def, uint4* __restrict__ Wt4)
{
    __shared__ __bf16 wrow[CK];
    const int o = blockIdx.x;
    const int t = threadIdx.x;
#pragma unroll
    for (int q = 0; q < 9; ++q)
        wrow[t * 9 + q] = (__bf16)w_def[(size_t)o * CK + t * 9 + q];
    __syncthreads();
    for (int s = t; s < 288; s += 256) {
        const int ch = s >> 3, g = s & 7;
        const int kk = ch >> 2, cg = ch & 3;
        bf16x8 v;
#pragma unroll
        for (int j = 0; j < 8; ++j)
            v[j] = wrow[(cg * 64 + g * 8 + j) * 9 + kk];
        Wt4[(size_t)ch * 2048 + o * 8 + (g ^ (o & 7))] = __builtin_bit_cast(uint4, v);
    }
}

// ---------------------------------------------------------------------------
// wprep_woff: offset-conv weights, bf16, M padded 18->32, same swizzle.
// ---------------------------------------------------------------------------
__global__ __launch_bounds__(256) void wprep_woff_kernel(
    const float* __restrict__ w_off, uint4* __restrict__ Woff4)
{
    const int ch = blockIdx.x;                 // 0..35
    const int t = threadIdx.x;
    const int o = t >> 3, g = t & 7;           // o 0..31
    const int kk = ch >> 2, cg = ch & 3;
    bf16x8 v;
#pragma unroll
    for (int j = 0; j < 8; ++j) {
        const int c = cg * 64 + g * 8 + j;
        v[j] = (o < NOFF) ? (__bf16)w_off[(size_t)o * CK + c * 9 + kk] : (__bf16)0.f;
    }
    Woff4[(size_t)ch * 256 + o * 8 + (g ^ (o & 7))] = __builtin_bit_cast(uint4, v);
}

// ---------------------------------------------------------------------------
// Offset conv via MFMA, barrier-free main loop (unchanged; proven r7).
// ---------------------------------------------------------------------------
__global__ __launch_bounds__(256, 4) void offs_mfma_kernel(
    const float* __restrict__ x, const uint4* __restrict__ Woff4,
    const float* __restrict__ b_off, float* __restrict__ offs)
{
    __shared__ float red[2][32][16];

    const int i = blockIdx.x;
    const int l = ((i & 7) << 6) + (i >> 3);   // bijective, 64 blocks/XCD
    const int ph = l & 1;
    const int bh = l >> 1;
    const int b = bh >> 6, h = bh & 63;

    const int t = threadIdx.x;
    const int w = t >> 6, lane = t & 63;
    const int l15 = lane & 15, l4 = lane >> 4;
    const int pxg = w & 1, kh = w >> 1;
    const int px = ph * 32 + pxg * 16 + l15;
    const float* xb = x + (size_t)b * C_ * HW;

    f32x4 acc0 = {0.f, 0.f, 0.f, 0.f}, acc1 = {0.f, 0.f, 0.f, 0.f};

    for (int kk = 0; kk < 9; ++kk) {
        const int ky = kk / 3, kx = kk - 3 * ky;
        const int y = h + ky - 1;
        const int col = px + kx - 1;
        const bool valid = (y >= 0) && (y < H_) && (col >= 0) && (col < W_);
#pragma unroll
        for (int cgl = 0; cgl < 2; ++cgl) {
            const int cg = kh * 2 + cgl;
            const int ch = kk * 4 + cg;
#pragma unroll
            for (int st = 0; st < 2; ++st) {
                const int g = st * 4 + l4;
                const int r0 = l15, r1 = 16 + l15;
                const bf16x8 a0 = __builtin_bit_cast(bf16x8,
                    Woff4[(size_t)ch * 256 + r0 * 8 + (g ^ (r0 & 7))]);
                const bf16x8 a1 = __builtin_bit_cast(bf16x8,
                    Woff4[(size_t)ch * 256 + r1 * 8 + (g ^ (r1 & 7))]);
                bf16x8 bF;
                if (valid) {
                    const float* p = xb + (size_t)(cg * 64 + g * 8) * HW + y * W_ + col;
#pragma unroll
                    for (int j = 0; j < 8; ++j)
                        bF[j] = (__bf16)p[(size_t)j * HW];
                } else {
#pragma unroll
                    for (int j = 0; j < 8; ++j) bF[j] = (__bf16)0.f;
                }
                acc0 = __builtin_amdgcn_mfma_f32_16x16x32_bf16(a0, bF, acc0, 0, 0, 0);
                acc1 = __builtin_amdgcn_mfma_f32_16x16x32_bf16(a1, bF, acc1, 0, 0, 0);
            }
        }
    }

    if (kh == 1) {
#pragma unroll
        for (int r = 0; r < 4; ++r) {
            red[pxg][l4 * 4 + r][l15] = acc0[r];
            red[pxg][16 + l4 * 4 + r][l15] = acc1[r];
        }
    }
    __syncthreads();
    if (kh == 0) {
#pragma unroll
        for (int ii = 0; ii < 2; ++ii) {
            const f32x4 a = ii ? acc1 : acc0;
#pragma unroll
            for (int r = 0; r < 4; ++r) {
                const int oc = ii * 16 + l4 * 4 + r;
                if (oc < NOFF) {
                    const float v = a[r] + red[pxg][oc][l15] + b_off[oc];
                    offs[((size_t)(bh * 64) + px) * NOFF + oc] = v;
                }
            }
        }
    }
}

// ---------------------------------------------------------------------------
// Deform conv, px-split v2: grid 512 = (b,h) x px-half, 512 threads (8 waves),
// 2 blocks/CU (74.25KB LDS).  Block tile 256o x 32px; wave w owns o=[w*32,+32).
// Sampling: threads t<256 only (32px x 8 granules, 8 ch/thread) -> chip-total
// sampling work halved vs o-split.  Offsets in LDS (r7 recipe: no private
// runtime arrays, no kk-loop unroll -> no spill).  Sl4 double-buffered ->
// ONE barrier per kk (40 barriers/block vs r7's 76).
// ---------------------------------------------------------------------------
__global__ __launch_bounds__(512, 4) void deform_mfma_kernel(
    const float* __restrict__ x, const float* __restrict__ offs,
    const uint4* __restrict__ Wt4, const float* __restrict__ b_def,
    float* __restrict__ out)
{
    __shared__ uint4 slab[4096];          // 64KB [8 rows][64 col][8 gran], gran=g^(col&7)
    __shared__ uint4 Sl4[2][256];         //  8KB double-buffered [32 px][8 gran]
    __shared__ float offs_lds[NOFF * 32]; // 2.25KB [oc][pl] for this px-half

    const int i = blockIdx.x;
    const int l = ((i & 7) << 6) + (i >> 3);   // px-halves of same (b,h) adjacent -> same XCD
    const int ph = l & 1;
    const int bh = l >> 1;
    const int b = bh >> 6, h = bh & 63;
    const int wb = h - 3;                 // slab window rows [wb, wb+7]

    const int t = threadIdx.x;
    const int lane = t & 63;
    const int w = t >> 6;                 // wave id = o-group (0..7)
    const int l15 = lane & 15, l4 = lane >> 4;

    const int sp = t & 63, sg8 = t >> 6;  // slab staging role (all 512 threads)
    const int pl = t & 31, sgs = (t >> 5) & 7;  // sampling role (t<256)
    const bool sampler = (t < 256);

    const float* xb = x + (size_t)b * C_ * HW;

    // ---- offsets -> LDS once ([oc][pl], 576 floats) ----
    for (int idx = t; idx < NOFF * 32; idx += 512) {
        const int p = idx & 31, oc = idx >> 5;
        offs_lds[oc * 32 + p] = offs[((size_t)(bh * 64) + ph * 32 + p) * NOFF + oc];
    }

    auto stage_slab = [&](int cg) {
        const float* xc = xb + (size_t)(cg * 64 + sg8 * 8) * HW;
#pragma unroll
        for (int r = 0; r < 8; ++r) {
            const int yc = min(max(wb + r, 0), H_ - 1);
            bf16x8 v;
#pragma unroll
            for (int j = 0; j < 8; ++j)
                v[j] = (__bf16)xc[(size_t)j * HW + yc * W_ + sp];
            slab[(r * 64 + sp) * 8 + (sg8 ^ (sp & 7))] = __builtin_bit_cast(uint4, v);
        }
    };

    f32x4 acc[2][2];
#pragma unroll
    for (int ii = 0; ii < 2; ++ii)
#pragma unroll
        for (int j = 0; j < 2; ++j) acc[ii][j] = f32x4{0.f, 0.f, 0.f, 0.f};

    for (int cg = 0; cg < 4; ++cg) {
        stage_slab(cg);                   // safe: prev cg's slab reads done before
        __syncthreads();                  //   last kk barrier; slab (+offs) visible
        const float* xsg = xb + (size_t)(cg * 64 + sgs * 8) * HW;  // slow-path base
        for (int kk = 0; kk < 9; ++kk) {  // NOT unrolled (r7 codegen recipe)
            const int buf = kk & 1;
            const int ch = kk * 4 + cg;
            // ---- A-frags from pre-swizzled global Wt4 (all threads, issue early) ----
            uint4 aR[2][2];
#pragma unroll
            for (int st = 0; st < 2; ++st) {
                const int g = st * 4 + l4;
#pragma unroll
                for (int ii = 0; ii < 2; ++ii) {
                    const int row = w * 32 + ii * 16 + l15;
                    aR[st][ii] = Wt4[(size_t)ch * 2048 + row * 8 + (g ^ (row & 7))];
                }
            }
            // ---- bilinear sampling (t<256): 32 px x 8 granules, 8 ch each ----
            if (sampler) {
                const int ky = kk / 3, kx = kk - 3 * ky;
                const float dy = offs_lds[(2 * kk) * 32 + pl];
                const float dx = offs_lds[(2 * kk + 1) * 32 + pl];
                const float py = (float)(h + ky - 1) + dy;
                const float pxf = (float)(ph * 32 + pl + kx - 1) + dx;
                const float y0f = floorf(py), x0f = floorf(pxf);
                const float ly = py - y0f, lx = pxf - x0f;
                const int y0 = (int)y0f, x0 = (int)x0f;
                const int y1 = y0 + 1, x1 = x0 + 1;
                const bool vy0 = (y0 >= 0) && (y0 < H_), vy1 = (y1 >= 0) && (y1 < H_);
                const bool vx0 = (x0 >= 0) && (x0 < W_), vx1 = (x1 >= 0) && (x1 < W_);
                const float w00 = (vy0 && vx0) ? (1.f - ly) * (1.f - lx) : 0.f;
                const float w01 = (vy0 && vx1) ? (1.f - ly) * lx : 0.f;
                const float w10 = (vy1 && vx0) ? ly * (1.f - lx) : 0.f;
                const float w11 = (vy1 && vx1) ? ly * lx : 0.f;
                bf16x8 sv;
                if (y0 >= wb && y0 <= wb + 6) {
                    const int s0 = y0 - wb;
                    const int xc0 = min(max(x0, 0), W_ - 1);
                    const int xc1 = min(max(x1, 0), W_ - 1);
                    const int gx0 = sgs ^ (xc0 & 7), gx1 = sgs ^ (xc1 & 7);
                    const bf16x8 c00 = __builtin_bit_cast(bf16x8, slab[(s0 * 64 + xc0) * 8 + gx0]);
                    const bf16x8 c01 = __builtin_bit_cast(bf16x8, slab[(s0 * 64 + xc1) * 8 + gx1]);
                    const bf16x8 c10 = __builtin_bit_cast(bf16x8, slab[((s0 + 1) * 64 + xc0) * 8 + gx0]);
                    const bf16x8 c11 = __builtin_bit_cast(bf16x8, slab[((s0 + 1) * 64 + xc1) * 8 + gx1]);
#pragma unroll
                    for (int j = 0; j < 8; ++j) {
                        const float v = w00 * (float)c00[j] + w01 * (float)c01[j]
                                      + w10 * (float)c10[j] + w11 * (float)c11[j];
                        sv[j] = (__bf16)v;
                    }
                } else {
                    const int y0c = min(max(y0, 0), H_ - 1), y1c = min(max(y1, 0), H_ - 1);
                    const int xc0 = min(max(x0, 0), W_ - 1), xc1 = min(max(x1, 0), W_ - 1);
                    const int i00 = y0c * W_ + xc0, i01 = y0c * W_ + xc1;
                    const int i10 = y1c * W_ + xc0, i11 = y1c * W_ + xc1;
#pragma unroll
                    for (int j = 0; j < 8; ++j) {
                        const float* p = xsg + (size_t)j * HW;
                        const float v = w00 * p[i00] + w01 * p[i01]
                                      + w10 * p[i10] + w11 * p[i11];
                        sv[j] = (__bf16)v;
                    }
                }
                Sl4[buf][pl * 8 + (sgs ^ (pl & 7))] = __builtin_bit_cast(uint4, sv);
            }
            __syncthreads();              // Sl4[buf] visible (1 barrier per kk)
            // ---- 2 K-steps of MFMA (all 8 waves) ----
#pragma unroll
            for (int st = 0; st < 2; ++st) {
                const int g = st * 4 + l4;
                bf16x8 bF[2];
#pragma unroll
                for (int j = 0; j < 2; ++j) {
                    const int pr = j * 16 + l15;           // local px 0..31
                    bF[j] = __builtin_bit_cast(bf16x8, Sl4[buf][pr * 8 + (g ^ (pr & 7))]);
                }
#pragma unroll
                for (int ii = 0; ii < 2; ++ii)
#pragma unroll
                    for (int j = 0; j < 2; ++j)
                        acc[ii][j] = __builtin_amdgcn_mfma_f32_16x16x32_bf16(
                            __builtin_bit_cast(bf16x8, aR[st][ii]), bF[j],
                            acc[ii][j], 0, 0, 0);
            }
        }
    }

    // ---- epilogue: bias + store (C/D: row=(l>>4)*4+r, col=l&15) ----
#pragma unroll
    for (int ii = 0; ii < 2; ++ii) {
#pragma unroll
        for (int r = 0; r < 4; ++r) {
            const int o = w * 32 + ii * 16 + l4 * 4 + r;
            const float bias = b_def[o];
#pragma unroll
            for (int j = 0; j < 2; ++j) {
                const int p = ph * 32 + j * 16 + l15;
                out[(((size_t)(b * O_ + o)) * H_ + h) * W_ + p] = acc[ii][j][r] + bias;
            }
        }
    }
}

// ---------------------------------------------------------------------------
extern "C" void kernel_launch(void* const* d_in, const int* in_sizes, int n_in,
                              void* d_out, int out_size, void* d_ws, size_t ws_size,
                              hipStream_t stream) {
    const float* x     = (const float*)d_in[0];
    const float* w_off = (const float*)d_in[1];
    const float* b_off = (const float*)d_in[2];
    const float* w_def = (const float*)d_in[3];
    const float* b_def = (const float*)d_in[4];
    float* out = (float*)d_out;

    // ws: Wt4 (73728 uint4 = 1.125MB) | Woff4 (9216 uint4 = 144KB) | offs (1.18MB)
    uint4* Wt4   = (uint4*)d_ws;
    uint4* Woff4 = Wt4 + 73728;
    float* offs  = (float*)(Woff4 + 9216);

    wprep_def_kernel<<<256, 256, 0, stream>>>(w_def, Wt4);
    wprep_woff_kernel<<<36, 256, 0, stream>>>(w_off, Woff4);
    offs_mfma_kernel<<<512, 256, 0, stream>>>(x, Woff4, b_off, offs);
    deform_mfma_kernel<<<512, 512, 0, stream>>>(x, offs, Wt4, b_def, out);
}